// Round 1
// baseline (1275.851 us; speedup 1.0000x reference)
//
#include <hip/hip_runtime.h>

// Problem constants (SparseConv2d: N=32, OC=IC=256, H=W=56, K=3, stride=1, pad=1)
constexpr int NB  = 32;
constexpr int ICC = 256;
constexpr int OCC = 256;
constexpr int HH  = 56;
constexpr int WWW = 56;
constexpr int HW  = HH * WWW;          // 3136
constexpr int CHW = ICC * HW;          // 802816
constexpr int TOTAL = NB * CHW;        // 25690112 input elements
constexpr int TAPS = ICC * 9;          // 2304 taps per output channel
constexpr int CAP  = 704;              // nnz capacity per oc (mean 230, sigma ~14)

constexpr int XG     = WWW / 4;        // 14 x-groups of 4 pixels per row
constexpr int GTOT   = NB * HH * XG;   // 25088 pixel-groups per oc
constexpr int CHUNKS = 49;             // 25088 / 512
constexpr int GPC    = 512;            // groups per chunk = 2 iters x 256 threads

// packed struct to allow 4B-aligned float4 loads (input taps are x-shifted by kw-1)
struct __attribute__((packed)) f4p { float4 v; };

__global__ __launch_bounds__(256) void sparse_conv_kernel(
    const float* __restrict__ in, const float* __restrict__ w,
    const float* __restrict__ bias, const int* __restrict__ mask,
    float* __restrict__ out)
{
  const int oc  = blockIdx.x;
  const int tid = threadIdx.x;

  __shared__ int   s_meta[CAP];
  __shared__ float s_val[CAP];
  __shared__ int   s_wtot[4];
  __shared__ int   s_cnt;

  // ---- per-block compaction of this oc's nonzero taps (ordered by ic,kh,kw) ----
  {
    const int ic   = tid;                       // 256 threads == 256 input channels
    const int base = oc * TAPS + ic * 9;
    float wv[9]; int mk[9];
    #pragma unroll
    for (int j = 0; j < 9; ++j) { wv[j] = w[base + j]; mk[j] = mask[base + j]; }
    int c = 0;
    #pragma unroll
    for (int j = 0; j < 9; ++j) c += (mk[j] != 0) ? 1 : 0;

    // wave-64 inclusive scan, then cross-wave combine
    const int lane = tid & 63, wvi = tid >> 6;
    int s = c;
    for (int d = 1; d < 64; d <<= 1) { int o = __shfl_up(s, d, 64); if (lane >= d) s += o; }
    if (lane == 63) s_wtot[wvi] = s;
    __syncthreads();
    int wbase = 0;
    for (int q = 0; q < wvi; ++q) wbase += s_wtot[q];
    int pos = wbase + s - c;                    // exclusive prefix over the block
    #pragma unroll
    for (int j = 0; j < 9; ++j) {
      if (mk[j] != 0) {
        const int kh = j / 3, kw = j - kh * 3;  // compile-time per unrolled j
        s_meta[pos] = (ic << 4) | (kh << 2) | kw;
        s_val[pos]  = wv[j];
        ++pos;
      }
    }
    if (tid == 255) s_cnt = pos;                // inclusive total
    __syncthreads();
  }

  const int   nn = s_cnt;
  const float bv = bias[oc];

  for (int it = 0; it < 2; ++it) {
    const int pg = blockIdx.y * GPC + it * 256 + tid;   // < GTOT by construction
    const int xg = pg % XG;
    const int t2 = pg / XG;
    const int y  = t2 % HH;
    const int n  = t2 / HH;
    const int x0 = xg * 4;

    const int ibase = n * CHW + y * WWW + x0;
    const int obase = (n * OCC + oc) * HW + y * WWW + x0;

    float a0 = bv, a1 = bv, a2 = bv, a3 = bv;
    // column-edge masks: only x=-1 (x0==0,kw==0,e==0) and x=56 (x0==52,kw==2,e==3) invalid
    const float fx0 = (x0 == 0)        ? 0.f : 1.f;
    const float fx3 = (x0 == WWW - 4)  ? 0.f : 1.f;

    // lanes whose clamped fast-path float4 load could still fall outside [0, TOTAL-4]
    const bool danger = (n == 0      && x0 == 0       && y <= 1) ||
                        (n == NB - 1 && x0 == WWW - 4 && y >= HH - 2);

    if (!danger) {
      for (int j = 0; j < nn; ++j) {
        const int   m   = __builtin_amdgcn_readfirstlane(s_meta[j]);
        const float val = __uint_as_float(__builtin_amdgcn_readfirstlane(__float_as_uint(s_val[j])));
        const int ic = m >> 4, kh = (m >> 2) & 3, kw = m & 3;
        const int soff = ic * HW + (kh - 1) * WWW + (kw - 1);   // scalar (SGPR) math
        const int iy   = y + kh - 1;
        const bool rok = (unsigned)iy < (unsigned)HH;
        int off = ibase + soff;
        off = rok ? off : 0;                     // safe address when row invalid
        const float4 v = ((const f4p*)(in + off))->v;
        const float va = rok ? val : 0.f;
        const float v0 = (kw == 0) ? va * fx0 : va;
        const float v3 = (kw == 2) ? va * fx3 : va;
        a0 += v0 * v.x;
        a1 += va * v.y;
        a2 += va * v.z;
        a3 += v3 * v.w;
      }
    } else {
      // fully-guarded scalar path for the few buffer-boundary lanes
      for (int j = 0; j < nn; ++j) {
        const int   m   = s_meta[j];
        const float val = s_val[j];
        const int ic = m >> 4, kh = (m >> 2) & 3, kw = m & 3;
        const int iy = y + kh - 1;
        #pragma unroll
        for (int e = 0; e < 4; ++e) {
          const int ix = x0 + e + kw - 1;
          const bool ok = ((unsigned)iy < (unsigned)HH) && ((unsigned)ix < (unsigned)WWW);
          int o = n * CHW + ic * HW + iy * WWW + ix;
          o = ok ? o : 0;
          const float xv = in[o];
          const float t  = ok ? val : 0.f;
          if      (e == 0) a0 += t * xv;
          else if (e == 1) a1 += t * xv;
          else if (e == 2) a2 += t * xv;
          else             a3 += t * xv;
        }
      }
    }

    float4 r; r.x = a0; r.y = a1; r.z = a2; r.w = a3;
    *(float4*)(out + obase) = r;                 // obase is a multiple of 4 -> 16B aligned
  }
}

extern "C" void kernel_launch(void* const* d_in, const int* in_sizes, int n_in,
                              void* d_out, int out_size, void* d_ws, size_t ws_size,
                              hipStream_t stream) {
  const float* in   = (const float*)d_in[0];
  const float* w    = (const float*)d_in[1];
  const float* bias = (const float*)d_in[2];
  const int*   mask = (const int*)d_in[3];
  float*       out  = (float*)d_out;

  dim3 grid(OCC, CHUNKS);   // blockIdx.x = oc (fastest) so all ocs of a chunk co-reside in L2
  sparse_conv_kernel<<<grid, 256, 0, stream>>>(in, w, bias, mask, out);
}